// Round 13
// baseline (1307.369 us; speedup 1.0000x reference)
//
#include <hip/hip_runtime.h>
#include <stdint.h>

typedef __bf16 bf16x8 __attribute__((ext_vector_type(8)));
typedef float f32x4 __attribute__((ext_vector_type(4)));
typedef unsigned short u16;
typedef u16 ushort8 __attribute__((ext_vector_type(8)));
typedef u16 ushort4v __attribute__((ext_vector_type(4)));

__device__ __forceinline__ u16 f2bf(float f) {
    uint32_t u = __builtin_bit_cast(uint32_t, f);
    u += 0x7FFFu + ((u >> 16) & 1u);   // RNE, inputs finite
    return (u16)(u >> 16);
}

__device__ __forceinline__ void gload16(const void* g, void* l) {
    __builtin_amdgcn_global_load_lds(
        reinterpret_cast<const __attribute__((address_space(1))) void*>(reinterpret_cast<uintptr_t>(g)),
        reinterpret_cast<__attribute__((address_space(3))) void*>(reinterpret_cast<uintptr_t>(l)),
        16, 0, 0);
}

#define BAR() asm volatile("s_barrier" ::: "memory")
#define SGBi(m, n) __builtin_amdgcn_sched_group_barrier((m), (n), 0)

// window with V vmem issues, 4 ds_read (next-phase A frags), 16 mfma
template <int V>
__device__ __forceinline__ void sgb_q() {
    SGBi(0x70, V);                       // VMEM pinned first
    SGBi(0x8, 2); SGBi(0x100, 1);
    SGBi(0x8, 2); SGBi(0x100, 1);
    SGBi(0x8, 2); SGBi(0x100, 1);
    SGBi(0x8, 2); SGBi(0x100, 1);
    SGBi(0x8, 8);
}
// q3: 2 vmem, {1 mfma,1 ds(afA next)}x4, 12 mfma, 8 ds (bfr next, WAR-pinned last)
__device__ __forceinline__ void sgb_q3() {
    SGBi(0x70, 2);
    SGBi(0x8, 1); SGBi(0x100, 1);
    SGBi(0x8, 1); SGBi(0x100, 1);
    SGBi(0x8, 1); SGBi(0x100, 1);
    SGBi(0x8, 1); SGBi(0x100, 1);
    SGBi(0x8, 12);
    SGBi(0x100, 8);
}

// ---------------------------------------------------------------------------
// gemm_moe: 640 threads = 8 GEMM waves + 2 builder waves. Grid (20, M/256).
// GEMM waves (0-7): Abuf[:,0:5120] = fw05_e * silu(X @ W1^T + b1), r9/r12
//   schedule (T1+T2+T5+T19, 4 merged windows/K-tile, vmcnt(4)@q2, reg
//   ping-pong A + B prefetch at q3). K=1024, NT=16. NO trickle.
// Builder waves (8-9): this block's 256x256 gated-feature tile,
//   Abuf[rowBase+r][5184 + bx*256 + c] = bf16(g05[r,qm] * feat_qm[r][dbase+c]),
//   paced on the SAME barriers (65 each side: 1 prologue + 64), one
//   software-pipelined slot per window (loads issued one barrier ahead).
//   vmcnt is PER-WAVE -> builder traffic never touches the GEMM waves'
//   counted ledger (this decoupling is what r6/r7's in-wave trickle lacked).
// ---------------------------------------------------------------------------
__global__ __launch_bounds__(640, 1)
void gemm_moe(const u16* __restrict__ A, const u16* __restrict__ B,
              u16* __restrict__ C, const float* __restrict__ bias,
              const float* __restrict__ fw05, const float* __restrict__ g05,
              const float* __restrict__ f0, const float* __restrict__ f1,
              const float* __restrict__ f2, const float* __restrict__ f3,
              const float* __restrict__ f4)
{
    __shared__ __align__(16) u16 As[2 * 256 * 64];
    __shared__ __align__(16) u16 Bs[2 * 256 * 64];

    const int t    = threadIdx.x;
    const int wave = t >> 6;

    const int gx  = gridDim.x;                 // 20
    const int nwg = gx * gridDim.y;
    int id  = blockIdx.y * gx + blockIdx.x;
    int swz = (nwg & 7) ? id : ((id & 7) * (nwg >> 3) + (id >> 3));
    const int bx = swz % gx;
    const int by = swz / gx;

    const size_t rowBase = (size_t)by * 256;
    const int    colBase = bx * 256;
    const int    qm      = bx >> 2;            // modality / expert group
    const float* fq = (qm == 0) ? f0 : (qm == 1) ? f1 : (qm == 2) ? f2
                      : (qm == 3) ? f3 : f4;
    const int dbase = (bx & 3) * 256;

    if (wave < 8) {
        // ================= GEMM waves: r12 schedule, no trickle =============
        const int lane = t & 63;
        const int l16  = lane & 15;
        const int lhi  = lane >> 4;
        const int wm   = wave >> 2;
        const int wn   = wave & 3;

        const int rl0 = t >> 3;
        const int ko0 = (t & 7) * 8;
        const int kos = ((t & 7) ^ (rl0 & 7)) * 8;

        const u16* aRow = A + (rowBase + rl0) * (size_t)1024 + kos;
        const u16* bRow = B + (size_t)(colBase + rl0) * 1024 + kos;
        u16* asW = As + rl0 * 64 + ko0;
        u16* bsW = Bs + rl0 * 64 + ko0;

#define STA(bufo, e, r0, r1)                                                     \
    do {                                                                         \
        gload16(aRow + (size_t)(r0) * 1024 + (e), asW + (bufo) + (r0) * 64);     \
        gload16(aRow + (size_t)(r1) * 1024 + (e), asW + (bufo) + (r1) * 64);     \
    } while (0)
#define STB(bufo, e, b0)                                                         \
    do {                                                                         \
        gload16(bRow + (size_t)(b0) * 1024 + (e), bsW + (bufo) + (b0) * 64);     \
        gload16(bRow + (size_t)((b0) + 64) * 1024 + (e),                         \
                bsW + (bufo) + ((b0) + 64) * 64);                                \
    } while (0)

        const int sw = l16 & 7;
        const u16* aRd0 = As + (wm * 128 + l16) * 64 + ((lhi ^ sw) * 8);
        const u16* aRd1 = As + (wm * 128 + l16) * 64 + (((lhi + 4) ^ sw) * 8);
        const u16* bRd0 = Bs + (wn * 64 + l16) * 64 + ((lhi ^ sw) * 8);
        const u16* bRd1 = Bs + (wn * 64 + l16) * 64 + (((lhi + 4) ^ sw) * 8);

#define RDAF(dst, cc, qq)                                                        \
    do {                                                                         \
        dst[0][0] = *(const bf16x8*)(aRd0 + (cc) + (2 * (qq) + 0) * 1024);       \
        dst[0][1] = *(const bf16x8*)(aRd1 + (cc) + (2 * (qq) + 0) * 1024);       \
        dst[1][0] = *(const bf16x8*)(aRd0 + (cc) + (2 * (qq) + 1) * 1024);       \
        dst[1][1] = *(const bf16x8*)(aRd1 + (cc) + (2 * (qq) + 1) * 1024);       \
    } while (0)
#define RDB(cc)                                                                  \
    do {                                                                         \
        _Pragma("unroll")                                                        \
        for (int ni = 0; ni < 4; ++ni) {                                         \
            bfr[ni][0] = *(const bf16x8*)(bRd0 + (cc) + ni * 1024);              \
            bfr[ni][1] = *(const bf16x8*)(bRd1 + (cc) + ni * 1024);              \
        }                                                                        \
    } while (0)
#define MMX(af, r0)                                                              \
    do {                                                                         \
        __builtin_amdgcn_s_setprio(1);                                           \
        _Pragma("unroll")                                                        \
        for (int s = 0; s < 2; ++s)                                              \
            _Pragma("unroll")                                                    \
            for (int ni = 0; ni < 4; ++ni)                                       \
                _Pragma("unroll")                                                \
                for (int kk = 0; kk < 2; ++kk)                                   \
                    acc[(r0) + s][ni] = __builtin_amdgcn_mfma_f32_16x16x32_bf16( \
                        af[s][kk], bfr[ni][kk], acc[(r0) + s][ni], 0, 0, 0);     \
        __builtin_amdgcn_s_setprio(0);                                           \
    } while (0)

        f32x4 acc[8][4];
#pragma unroll
        for (int i = 0; i < 8; i++)
#pragma unroll
            for (int j = 0; j < 4; j++)
                acc[i][j] = (f32x4){0.f, 0.f, 0.f, 0.f};

        // prologue: tile0 full -> buf0; tile1 {Bh0,Bh1,Ah0} -> buf1
        STA(0, 0, 0, 128);
        STA(0, 0, 64, 192);
        STB(0, 0, 0);
        STB(0, 0, 128);
        STB(16384, 64, 0);
        STB(16384, 64, 128);
        STA(16384, 64, 0, 128);
        asm volatile("s_waitcnt vmcnt(6)" ::: "memory");
        BAR();                                   // [barrier 1]

        bf16x8 afA[2][2], afB[2][2], bfr[4][2];
        RDAF(afA, 0, 0);
        RDB(0);

        for (int tt = 0; tt < 16; ++tt) {        // [barriers 2..65: 4/tile]
            const int c  = (tt & 1) << 14;
            const int cn = c ^ 16384;
            const int e1 = ((tt + 1 < 16) ? tt + 1 : 15) << 6;
            const int e2 = ((tt + 2 < 16) ? tt + 2 : 15) << 6;

            // q0
            STA(cn, e1, 64, 192);
            RDAF(afB, c, 1);
            MMX(afA, 0);
            sgb_q<2>();
            BAR();
            // q1
            STB(c, e2, 0);
            RDAF(afA, c, 2);
            MMX(afB, 2);
            sgb_q<2>();
            BAR();
            // q2
            STB(c, e2, 128);
            RDAF(afB, c, 3);
            MMX(afA, 4);
            sgb_q<2>();
            asm volatile("s_waitcnt vmcnt(4)" ::: "memory");
            BAR();
            // q3
            STA(c, e2, 0, 128);
            RDAF(afA, cn, 0);
            MMX(afB, 6);
            RDB(cn);
            sgb_q3();
            BAR();
        }

        const int orow = wm * 128 + lhi * 4;
        const int ocol = colBase + wn * 64 + l16;
#pragma unroll
        for (int mi = 0; mi < 8; mi++) {
#pragma unroll
            for (int j = 0; j < 4; j++) {
                size_t r = rowBase + orow + mi * 16 + j;
                float w = fw05[r * 5 + qm];
#pragma unroll
                for (int ni = 0; ni < 4; ni++) {
                    int cc = ocol + ni * 16;
                    float v = acc[mi][ni][j] + bias[cc];
                    float s = v / (1.f + __expf(-v));   // silu
                    C[r * (size_t)10368 + cc] = f2bf(w * s);
                }
            }
        }
#undef STA
#undef STB
#undef RDAF
#undef RDB
#undef MMX
    } else {
        // ================= builder waves: 64 paced slots ====================
        const int bt   = t - 512;                // 0..127
        const int rof  = bt >> 5;                // row offset within slot
        const int bcol = (bt & 31) * 8;

        // preload slot 0 (before prologue barrier)
        size_t r0 = rowBase + rof;
        f32x4 la  = *(const f32x4*)(fq + r0 * 1024 + dbase + bcol);
        f32x4 lb  = *(const f32x4*)(fq + r0 * 1024 + dbase + bcol + 4);
        float lg  = g05[r0 * 5 + qm];
        size_t rcur = r0;

        BAR();                                   // [barrier 1]

        for (int s = 0; s < 64; ++s) {           // [barriers 2..65]
            ushort8 v;
            v[0] = f2bf(lg * la[0]); v[1] = f2bf(lg * la[1]);
            v[2] = f2bf(lg * la[2]); v[3] = f2bf(lg * la[3]);
            v[4] = f2bf(lg * lb[0]); v[5] = f2bf(lg * lb[1]);
            v[6] = f2bf(lg * lb[2]); v[7] = f2bf(lg * lb[3]);
            *(ushort8*)(C + rcur * 10368 + 5184 + colBase + bcol) = v;

            const int s2 = (s + 1 < 64) ? s + 1 : 63;   // clamped, no branch
            size_t rn = rowBase + s2 * 4 + rof;
            la = *(const f32x4*)(fq + rn * 1024 + dbase + bcol);
            lb = *(const f32x4*)(fq + rn * 1024 + dbase + bcol + 4);
            lg = g05[rn * 5 + qm];
            rcur = rn;
            BAR();
        }
    }
}

// ---------------------------------------------------------------------------
// gemm_out: C[M,1024] f32 = A[M,K] @ B[1024,K]^T, r9/r12 schedule (unchanged).
// 512 threads = 8 waves, K % 64 == 0 (K = 10368 here).
// ---------------------------------------------------------------------------
__global__ __launch_bounds__(512, 2)
void gemm_out(const u16* __restrict__ A, int lda,
              const u16* __restrict__ B, int ldb, int K,
              float* __restrict__ C, int ldc)
{
    __shared__ __align__(16) u16 As[2 * 256 * 64];
    __shared__ __align__(16) u16 Bs[2 * 256 * 64];

    const int t    = threadIdx.x;
    const int lane = t & 63;
    const int wave = t >> 6;
    const int l16  = lane & 15;
    const int lhi  = lane >> 4;
    const int wm   = wave >> 2;
    const int wn   = wave & 3;

    const int gx  = gridDim.x;
    const int nwg = gx * gridDim.y;
    int id  = blockIdx.y * gx + blockIdx.x;
    int swz = (nwg & 7) ? id : ((id & 7) * (nwg >> 3) + (id >> 3));
    const int bx = swz % gx;
    const int by = swz / gx;

    const size_t rowBase = (size_t)by * 256;
    const int    colBase = bx * 256;
    const int    NT      = K >> 6;

    const int rl0 = t >> 3;
    const int ko0 = (t & 7) * 8;
    const int kos = ((t & 7) ^ (rl0 & 7)) * 8;

    const u16* aRow = A + (rowBase + rl0) * (size_t)lda + kos;
    const u16* bRow = B + (size_t)(colBase + rl0) * ldb + kos;
    u16* asW = As + rl0 * 64 + ko0;
    u16* bsW = Bs + rl0 * 64 + ko0;

#define STA(bufo, e, r0, r1)                                                     \
    do {                                                                         \
        gload16(aRow + (size_t)(r0) * lda + (e), asW + (bufo) + (r0) * 64);      \
        gload16(aRow + (size_t)(r1) * lda + (e), asW + (bufo) + (r1) * 64);      \
    } while (0)
#define STB(bufo, e, b0)                                                         \
    do {                                                                         \
        gload16(bRow + (size_t)(b0) * ldb + (e), bsW + (bufo) + (b0) * 64);      \
        gload16(bRow + (size_t)((b0) + 64) * ldb + (e),                          \
                bsW + (bufo) + ((b0) + 64) * 64);                                \
    } while (0)

    const int sw = l16 & 7;
    const u16* aRd0 = As + (wm * 128 + l16) * 64 + ((lhi ^ sw) * 8);
    const u16* aRd1 = As + (wm * 128 + l16) * 64 + (((lhi + 4) ^ sw) * 8);
    const u16* bRd0 = Bs + (wn * 64 + l16) * 64 + ((lhi ^ sw) * 8);
    const u16* bRd1 = Bs + (wn * 64 + l16) * 64 + (((lhi + 4) ^ sw) * 8);

#define RDAF(dst, cc, qq)                                                        \
    do {                                                                         \
        dst[0][0] = *(const bf16x8*)(aRd0 + (cc) + (2 * (qq) + 0) * 1024);       \
        dst[0][1] = *(const bf16x8*)(aRd1 + (cc) + (2 * (qq) + 0) * 1024);       \
        dst[1][0] = *(const bf16x8*)(aRd0 + (cc) + (2 * (qq) + 1) * 1024);       \
        dst[1][1] = *(const bf16x8*)(aRd1 + (cc) + (2 * (qq) + 1) * 1024);       \
    } while (0)
#define RDB(cc)                                                                  \
    do {                                                                         \
        _Pragma("unroll")                                                        \
        for (int ni = 0; ni < 4; ++ni) {                                         \
            bfr[ni][0] = *(const bf16x8*)(bRd0 + (cc) + ni * 1024);              \
            bfr[ni][1] = *(const bf16x8*)(bRd1 + (cc) + ni * 1024);              \
        }                                                                        \
    } while (0)
#define MMX(af, r0)                                                              \
    do {                                                                         \
        __builtin_amdgcn_s_setprio(1);                                           \
        _Pragma("unroll")                                                        \
        for (int s = 0; s < 2; ++s)                                              \
            _Pragma("unroll")                                                    \
            for (int ni = 0; ni < 4; ++ni)                                       \
                _Pragma("unroll")                                                \
                for (int kk = 0; kk < 2; ++kk)                                   \
                    acc[(r0) + s][ni] = __builtin_amdgcn_mfma_f32_16x16x32_bf16( \
                        af[s][kk], bfr[ni][kk], acc[(r0) + s][ni], 0, 0, 0);     \
        __builtin_amdgcn_s_setprio(0);                                           \
    } while (0)

    f32x4 acc[8][4];
#pragma unroll
    for (int i = 0; i < 8; i++)
#pragma unroll
        for (int j = 0; j < 4; j++)
            acc[i][j] = (f32x4){0.f, 0.f, 0.f, 0.f};

    STA(0, 0, 0, 128);
    STA(0, 0, 64, 192);
    STB(0, 0, 0);
    STB(0, 0, 128);
    STB(16384, 64, 0);
    STB(16384, 64, 128);
    STA(16384, 64, 0, 128);
    asm volatile("s_waitcnt vmcnt(6)" ::: "memory");
    BAR();

    bf16x8 afA[2][2], afB[2][2], bfr[4][2];
    RDAF(afA, 0, 0);
    RDB(0);

    for (int tt = 0; tt < NT; ++tt) {
        const int c  = (tt & 1) << 14;
        const int cn = c ^ 16384;
        const int e1 = ((tt + 1 < NT) ? tt + 1 : NT - 1) << 6;
        const int e2 = ((tt + 2 < NT) ? tt + 2 : NT - 1) << 6;

        STA(cn, e1, 64, 192);
        RDAF(afB, c, 1);
        MMX(afA, 0);
        sgb_q<2>();
        BAR();

        STB(c, e2, 0);
        RDAF(afA, c, 2);
        MMX(afB, 2);
        sgb_q<2>();
        BAR();

        STB(c, e2, 128);
        RDAF(afB, c, 3);
        MMX(afA, 4);
        sgb_q<2>();
        asm volatile("s_waitcnt vmcnt(4)" ::: "memory");
        BAR();

        STA(c, e2, 0, 128);
        RDAF(afA, cn, 0);
        MMX(afB, 6);
        RDB(cn);
        sgb_q3();
        BAR();
    }

    const int orow = wm * 128 + lhi * 4;
    const int ocol = colBase + wn * 64 + l16;
#pragma unroll
    for (int mi = 0; mi < 8; mi++) {
#pragma unroll
        for (int j = 0; j < 4; j++) {
            size_t r = rowBase + orow + mi * 16 + j;
#pragma unroll
            for (int ni = 0; ni < 4; ni++) {
                size_t idx = r * (size_t)ldc + (ocol + ni * 16);
                C[idx] = acc[mi][ni][j];
            }
        }
    }
#undef STA
#undef STB
#undef RDAF
#undef RDB
#undef MMX
}

// ---------------------------------------------------------------------------
// Router: logits[r][0..79] = x[r] . {Wsoft(5) | Wsparse(5) | m_key(64) | Wg(5)}
// Also emits Xbf = bf16(x).
// ---------------------------------------------------------------------------
__global__ __launch_bounds__(256)
void router_kernel(const float* __restrict__ x,
                   const float* __restrict__ Wsoft, const float* __restrict__ Wsparse,
                   const float* __restrict__ m_key, const float* __restrict__ Wg,
                   float* __restrict__ logits, u16* __restrict__ Xbf)
{
    __shared__ float Xs[128][66];
    __shared__ float Ws[80][132];

    const int t    = threadIdx.x;
    const int lane = t & 63;
    const int wave = t >> 6;
    const int row0 = blockIdx.x * 64;

    float acc[20];
#pragma unroll
    for (int c = 0; c < 20; c++) acc[c] = 0.f;

    for (int k0 = 0; k0 < 1024; k0 += 128) {
#pragma unroll
        for (int i = 0; i < 8; i++) {
            int f4 = i * 256 + t;
            int r  = f4 >> 5;
            int kk = (f4 & 31) * 4;
            f32x4 v = *(const f32x4*)(x + (size_t)(row0 + r) * 1024 + k0 + kk);
            Xs[kk + 0][r] = v[0]; Xs[kk + 1][r] = v[1];
            Xs[kk + 2][r] = v[2]; Xs[kk + 3][r] = v[3];
            ushort4v o4;
            o4[0] = f2bf(v[0]); o4[1] = f2bf(v[1]);
            o4[2] = f2bf(v[2]); o4[3] = f2bf(v[3]);
            *(ushort4v*)(Xbf + (size_t)(row0 + r) * 1024 + k0 + kk) = o4;
        }
#pragma unroll
        for (int i = 0; i < 10; i++) {
            int f4 = i * 256 + t;
            int j  = f4 >> 5;
            int kk = (f4 & 31) * 4;
            const float* src;
            if      (j < 5)  src = Wsoft   + (size_t)j * 1024;
            else if (j < 10) src = Wsparse + (size_t)(j - 5) * 1024;
            else if (j < 74) src = m_key   + (size_t)(j - 10) * 1024;
            else             src = Wg      + (size_t)(j - 74) * 1024;
            *(f32x4*)&Ws[j][kk] = *(const f32x4*)(src + k0 + kk);
        }
        __syncthreads();

        for (int k4 = 0; k4 < 32; k4++) {
            float x0 = Xs[k4 * 4 + 0][lane];
            float x1 = Xs[k4 * 4 + 1][lane];
            float x2 = Xs[k4 * 4 + 2][lane];
            float x3 = Xs[k4 * 4 + 3][lane];
#pragma unroll
            for (int c = 0; c < 20; c++) {
                f32x4 w = *(const f32x4*)&Ws[wave * 20 + c][k4 * 4];
                acc[c] += x0 * w[0] + x1 * w[1] + x2 * w[2] + x3 * w[3];
            }
        }
        __syncthreads();
    }

    float* dst = logits + (size_t)(row0 + lane) * 80 + wave * 20;
#pragma unroll
    for (int c = 0; c < 20; c++) dst[c] = acc[c];
}

// ---------------------------------------------------------------------------
// Finalize: fw05/g05, plus Abuf tail columns (ld 10368)
// ---------------------------------------------------------------------------
__global__ __launch_bounds__(256)
void finalize_kernel(const float* __restrict__ logits, const float* __restrict__ m_val,
                     const float* __restrict__ bsoft, const float* __restrict__ bsparse,
                     const float* __restrict__ bg,
                     float* __restrict__ fw05, float* __restrict__ g05,
                     u16* __restrict__ Abuf, int NC)
{
    __shared__ float mv[320];
    for (int i = threadIdx.x; i < 320; i += 256) mv[i] = m_val[i];
    __syncthreads();

    int idx = blockIdx.x * 256 + threadIdx.x;
    if (idx >= NC) return;
    const float* L = logits + (size_t)idx * 80;

    float sl[5];
#pragma unroll
    for (int e = 0; e < 5; e++) sl[e] = L[e] + bsoft[e];
    float sm = sl[0];
#pragma unroll
    for (int e = 1; e < 5; e++) sm = fmaxf(sm, sl[e]);
    float ssum = 0.f, sw[5];
#pragma unroll
    for (int e = 0; e < 5; e++) { sw[e] = __expf(sl[e] - sm); ssum += sw[e]; }
    float sinv = 1.f / ssum;

    int am = 0; float bv = L[5] + bsparse[0];
#pragma unroll
    for (int e = 1; e < 5; e++) {
        float v = L[5 + e] + bsparse[e];
        if (v > bv) { bv = v; am = e; }
    }

    float amax = -1e30f;
    for (int m = 0; m < 64; m++) amax = fmaxf(amax, L[10 + m] * 0.03125f);
    float asum = 0.f, mw[5] = {0.f, 0.f, 0.f, 0.f, 0.f};
    for (int m = 0; m < 64; m++) {
        float a = __expf(L[10 + m] * 0.03125f - amax);
        asum += a;
#pragma unroll
        for (int e = 0; e < 5; e++) mw[e] += a * mv[m * 5 + e];
    }
    float ainv = 1.f / asum;
#pragma unroll
    for (int e = 0; e < 5; e++) mw[e] *= ainv;
    float mm = mw[0];
#pragma unroll
    for (int e = 1; e < 5; e++) mm = fmaxf(mm, mw[e]);
    float msum = 0.f, me[5];
#pragma unroll
    for (int e = 0; e < 5; e++) { me[e] = __expf(mw[e] - mm); msum += me[e]; }
    float minv = 1.f / msum;

    u16* ta = Abuf + (size_t)idx * 10368;
#pragma unroll
    for (int e = 0; e < 5; e++) {
        float fv = 0.125f * ((e == am) ? 1.f : 0.f) + 0.125f * sw[e] * sinv
                 + 0.25f * me[e] * minv;
        fw05[(size_t)idx * 5 + e] = fv;
        ta[5120 + e] = f2bf(fv);
    }
#pragma unroll
    for (int q = 0; q < 5; q++)
        g05[(size_t)idx * 5 + q] = 0.5f / (1.f + __expf(-(L[74 + q] + bg[q])));

    for (int j = 5125; j < 5184; j++) ta[j] = 0;
    ta[10304] = f2bf(0.5f);
    for (int j = 10305; j < 10368; j++) ta[j] = 0;
}

// ---------------------------------------------------------------------------
__global__ __launch_bounds__(256)
void cast_bf16_kernel(const float* __restrict__ src, u16* __restrict__ dst, size_t n)
{
    size_t i = ((size_t)blockIdx.x * 256 + threadIdx.x) * 8;
    if (i >= n) return;
    f32x4 a = *(const f32x4*)(src + i);
    f32x4 b = *(const f32x4*)(src + i + 4);
    ushort8 o;
    o[0] = f2bf(a[0]); o[1] = f2bf(a[1]); o[2] = f2bf(a[2]); o[3] = f2bf(a[3]);
    o[4] = f2bf(b[0]); o[5] = f2bf(b[1]); o[6] = f2bf(b[2]); o[7] = f2bf(b[3]);
    *(ushort8*)(dst + i) = o;
}

// Wcat[o][c], ld 10368: c<5120: W2[e][o][d]; c=5120+e: b2[e][o]; c<5184: 0;
// c2=c-5184<5120: Wf[o][c2]; c2==5120: bf[o]; else 0.
__global__ __launch_bounds__(256)
void prep_wcat(const float* __restrict__ W2, const float* __restrict__ b2,
               const float* __restrict__ Wf, const float* __restrict__ bfias,
               u16* __restrict__ out)
{
    size_t tid = (size_t)blockIdx.x * 256 + threadIdx.x;   // 1024*1296
    int o  = (int)(tid / 1296);
    int c0 = (int)(tid % 1296) * 8;
    ushort8 v;
    if (c0 + 8 <= 5120) {
        int e = c0 >> 10, d = c0 & 1023;
        const float* s = W2 + ((size_t)e * 1024 + o) * 1024 + d;
        f32x4 a = *(const f32x4*)s;
        f32x4 b = *(const f32x4*)(s + 4);
        v[0] = f2bf(a[0]); v[1] = f2bf(a[1]); v[2] = f2bf(a[2]); v[3] = f2bf(a[3]);
        v[4] = f2bf(b[0]); v[5] = f2bf(b[1]); v[6] = f2bf(b[2]); v[7] = f2bf(b[3]);
    } else if (c0 < 5184) {
#pragma unroll
        for (int jj = 0; jj < 8; jj++) {
            int c = c0 + jj;
            float f = (c >= 5120 && c < 5125) ? b2[(size_t)(c - 5120) * 1024 + o] : 0.f;
            v[jj] = f2bf(f);
        }
    } else {
        int c2 = c0 - 5184;
        if (c2 + 8 <= 5120) {
            const float* s = Wf + (size_t)o * 5120 + c2;
            f32x4 a = *(const f32x4*)s;
            f32x4 b = *(const f32x4*)(s + 4);
            v[0] = f2bf(a[0]); v[1] = f2bf(a[1]); v[2] = f2bf(a[2]); v[3] = f2bf(a[3]);
            v[4] = f2bf(b[0]); v[5] = f2bf(b[1]); v[6] = f2bf(b[2]); v[7] = f2bf(b[3]);
        } else {
#pragma unroll
            for (int jj = 0; jj < 8; jj++) {
                int cj = c2 + jj;
                v[jj] = f2bf((cj == 5120) ? bfias[o] : 0.f);
            }
        }
    }
    *(ushort8*)(out + (size_t)o * 10368 + c0) = v;
}

// ---------------------------------------------------------------------------
extern "C" void kernel_launch(void* const* d_in, const int* in_sizes, int n_in,
                              void* d_out, int out_size, void* d_ws, size_t ws_size,
                              hipStream_t stream)
{
    (void)in_sizes; (void)n_in; (void)out_size;

    const float* x      = (const float*)d_in[0];
    const float* spect  = (const float*)d_in[1];
    const float* wavef  = (const float*)d_in[2];
    const float* pitch  = (const float*)d_in[3];
    const float* envel  = (const float*)d_in[4];
    const float* phase  = (const float*)d_in[5];
    const float* Wsoft  = (const float*)d_in[6];
    const float* bsoft  = (const float*)d_in[7];
    const float* Wsparse= (const float*)d_in[8];
    const float* bsparse= (const float*)d_in[9];
    const float* m_key  = (const float*)d_in[10];
    const float* m_val  = (const float*)d_in[11];
    const float* W1     = (const float*)d_in[12];
    const float* b1     = (const float*)d_in[13];
    const float* W2     = (const float*)d_in[14];
    const float* b2     = (const float*)d_in[15];
    const float* Wg     = (const float*)d_in[16];
    const float* bg     = (const float*)d_in[17];
    const float* Wf     = (const float*)d_in[18];
    const float* bfias  = (const float*)d_in[19];
    float* out = (float*)d_out;

    const int N = 16384;

    // per-row: Xbf 2048 + Abuf 20736 + logits 320 + fw05 20 + g05 20 = 23144 B
    size_t fixed = (size_t)5 * 1024 * 1024 * 2 + (size_t)1024 * 10368 * 2;
    int NC = 16384;
    while (NC > 256 && fixed + (size_t)NC * 23144 > ws_size) NC >>= 1;

    char* p = (char*)d_ws;
    u16* W1bf = (u16*)p; p += (size_t)5 * 1024 * 1024 * 2;
    u16* Wcat = (u16*)p; p += (size_t)1024 * 10368 * 2;
    u16* Xbf  = (u16*)p; p += (size_t)NC * 1024 * 2;
    u16* Abuf = (u16*)p; p += (size_t)NC * 10368 * 2;
    float* logits = (float*)p; p += (size_t)NC * 80 * 4;
    float* fw05   = (float*)p; p += (size_t)NC * 5 * 4;
    float* g05    = (float*)p; p += (size_t)NC * 5 * 4;

    // one-time weight prep (W1 flat IS the [5120][1024] concat: row e*1024+o)
    cast_bf16_kernel<<<2560, 256, 0, stream>>>(W1, W1bf, (size_t)5 * 1024 * 1024);
    prep_wcat<<<5184, 256, 0, stream>>>(W2, b2, Wf, bfias, Wcat);

    for (int n0 = 0; n0 < N; n0 += NC) {
        const size_t off = (size_t)n0 * 1024;

        router_kernel<<<NC / 64, 256, 0, stream>>>(x + off, Wsoft, Wsparse, m_key, Wg,
                                                   logits, Xbf);
        finalize_kernel<<<(NC + 255) / 256, 256, 0, stream>>>(
            logits, m_val, bsoft, bsparse, bg, fw05, g05, Abuf, NC);

        // Abuf[:,0:5120] = fw05_e * silu(X @ W1^T + b1) (8 GEMM waves) and
        // Abuf[:,5184:10304] = g * feat (2 builder waves, barrier-paced)
        gemm_moe<<<dim3(20, NC / 256), 640, 0, stream>>>(
            Xbf, W1bf, Abuf, b1, fw05, g05,
            spect + off, wavef + off, pitch + off, envel + off, phase + off);

        // out = 0.5*moe + 0.5*fused in one K=10368 GEMM
        gemm_out<<<dim3(4, NC / 256), 512, 0, stream>>>(
            Abuf, 10368, Wcat, 10368, 10368, out + off, 1024);
    }
}

// Round 15
// 653.331 us; speedup vs baseline: 2.0011x; 2.0011x over previous
//
#include <hip/hip_runtime.h>
#include <stdint.h>

typedef __bf16 bf16x8 __attribute__((ext_vector_type(8)));
typedef float f32x4 __attribute__((ext_vector_type(4)));
typedef unsigned short u16;
typedef u16 ushort8 __attribute__((ext_vector_type(8)));
typedef u16 ushort4v __attribute__((ext_vector_type(4)));

__device__ __forceinline__ u16 f2bf(float f) {
    uint32_t u = __builtin_bit_cast(uint32_t, f);
    u += 0x7FFFu + ((u >> 16) & 1u);   // RNE, inputs finite
    return (u16)(u >> 16);
}

__device__ __forceinline__ void gload16(const void* g, void* l) {
    __builtin_amdgcn_global_load_lds(
        reinterpret_cast<const __attribute__((address_space(1))) void*>(reinterpret_cast<uintptr_t>(g)),
        reinterpret_cast<__attribute__((address_space(3))) void*>(reinterpret_cast<uintptr_t>(l)),
        16, 0, 0);
}

#define BAR() asm volatile("s_barrier" ::: "memory")
#define SGBi(m, n) __builtin_amdgcn_sched_group_barrier((m), (n), 0)

// window with V vmem issues, 4 ds_read (next-phase A frags), 16 mfma
template <int V>
__device__ __forceinline__ void sgb_q() {
    SGBi(0x70, V);                       // VMEM pinned first
    SGBi(0x8, 2); SGBi(0x100, 1);
    SGBi(0x8, 2); SGBi(0x100, 1);
    SGBi(0x8, 2); SGBi(0x100, 1);
    SGBi(0x8, 2); SGBi(0x100, 1);
    SGBi(0x8, 8);
}
// q3: 2 vmem, {1 mfma,1 ds(afA next)}x4, 12 mfma, 8 ds (bfr next, WAR-pinned last)
__device__ __forceinline__ void sgb_q3() {
    SGBi(0x70, 2);
    SGBi(0x8, 1); SGBi(0x100, 1);
    SGBi(0x8, 1); SGBi(0x100, 1);
    SGBi(0x8, 1); SGBi(0x100, 1);
    SGBi(0x8, 1); SGBi(0x100, 1);
    SGBi(0x8, 12);
    SGBi(0x100, 8);
}

// ---------------------------------------------------------------------------
// GEMM: C[M,NN] = A[M,K] @ B[NN,K]^T (bf16, K-contiguous rows), K % 64 == 0.
// 256x256 tile, BK=64, 512 threads = 8 waves (2M x 4N), 128x64 per wave.
// T1 XCD swizzle, T2 LDS XOR-swizzle, T5 setprio, T19 sched_group_barrier.
// r9/r12 schedule (FINAL): 4 merged windows/K-tile, vmcnt(4)@q2, q3
// prefetches tile t+1's A-q0 frags (ping-pong regs) + B frags (WAR-pinned).
// MODE 0 (K=1024, NT=16 REQUIRED): bf16 C = f2bf(fw05*silu(acc+bias)) +
//   trickled gated-feature build (1 chunk/thread/tile, issued oldest-first).
// MODE 1: f32 C = acc
// ---------------------------------------------------------------------------
template <int MODE>
__global__ __launch_bounds__(512, 2)
void gemm256(const u16* __restrict__ A, int lda,
             const u16* __restrict__ B, int ldb, int K,
             void* __restrict__ Cout, int ldc,
             const float* __restrict__ bias, const float* __restrict__ fw05,
             const float* __restrict__ g05,
             const float* __restrict__ f0, const float* __restrict__ f1,
             const float* __restrict__ f2, const float* __restrict__ f3,
             const float* __restrict__ f4)
{
    __shared__ __align__(16) u16 As[2 * 256 * 64];
    __shared__ __align__(16) u16 Bs[2 * 256 * 64];

    const int t    = threadIdx.x;
    const int lane = t & 63;
    const int wave = t >> 6;
    const int l16  = lane & 15;
    const int lhi  = lane >> 4;
    const int wm   = wave >> 2;
    const int wn   = wave & 3;

    const int gx  = gridDim.x;
    const int nwg = gx * gridDim.y;
    int id  = blockIdx.y * gx + blockIdx.x;
    int swz = (nwg & 7) ? id : ((id & 7) * (nwg >> 3) + (id >> 3));
    const int bx = swz % gx;
    const int by = swz / gx;

    const size_t rowBase = (size_t)by * 256;
    const int    colBase = bx * 256;
    const int    NT      = K >> 6;

    const int rl0 = t >> 3;
    const int ko0 = (t & 7) * 8;
    const int kos = ((t & 7) ^ (rl0 & 7)) * 8;

    const u16* aRow = A + (rowBase + rl0) * (size_t)lda + kos;
    const u16* bRow = B + (size_t)(colBase + rl0) * ldb + kos;
    u16* asW = As + rl0 * 64 + ko0;
    u16* bsW = Bs + rl0 * 64 + ko0;

#define STA(bufo, e, r0, r1)                                                     \
    do {                                                                         \
        gload16(aRow + (size_t)(r0) * lda + (e), asW + (bufo) + (r0) * 64);      \
        gload16(aRow + (size_t)(r1) * lda + (e), asW + (bufo) + (r1) * 64);      \
    } while (0)
#define STB(bufo, e, b0)                                                         \
    do {                                                                         \
        gload16(bRow + (size_t)(b0) * ldb + (e), bsW + (bufo) + (b0) * 64);      \
        gload16(bRow + (size_t)((b0) + 64) * ldb + (e),                          \
                bsW + (bufo) + ((b0) + 64) * 64);                                \
    } while (0)

    const int sw = l16 & 7;
    const u16* aRd0 = As + (wm * 128 + l16) * 64 + ((lhi ^ sw) * 8);
    const u16* aRd1 = As + (wm * 128 + l16) * 64 + (((lhi + 4) ^ sw) * 8);
    const u16* bRd0 = Bs + (wn * 64 + l16) * 64 + ((lhi ^ sw) * 8);
    const u16* bRd1 = Bs + (wn * 64 + l16) * 64 + (((lhi + 4) ^ sw) * 8);

#define RDAF(dst, cc, qq)                                                        \
    do {                                                                         \
        dst[0][0] = *(const bf16x8*)(aRd0 + (cc) + (2 * (qq) + 0) * 1024);       \
        dst[0][1] = *(const bf16x8*)(aRd1 + (cc) + (2 * (qq) + 0) * 1024);       \
        dst[1][0] = *(const bf16x8*)(aRd0 + (cc) + (2 * (qq) + 1) * 1024);       \
        dst[1][1] = *(const bf16x8*)(aRd1 + (cc) + (2 * (qq) + 1) * 1024);       \
    } while (0)
#define RDB(cc)                                                                  \
    do {                                                                         \
        _Pragma("unroll")                                                        \
        for (int ni = 0; ni < 4; ++ni) {                                         \
            bfr[ni][0] = *(const bf16x8*)(bRd0 + (cc) + ni * 1024);              \
            bfr[ni][1] = *(const bf16x8*)(bRd1 + (cc) + ni * 1024);              \
        }                                                                        \
    } while (0)
#define MMX(af, r0)                                                              \
    do {                                                                         \
        __builtin_amdgcn_s_setprio(1);                                           \
        _Pragma("unroll")                                                        \
        for (int s = 0; s < 2; ++s)                                              \
            _Pragma("unroll")                                                    \
            for (int ni = 0; ni < 4; ++ni)                                       \
                _Pragma("unroll")                                                \
                for (int kk = 0; kk < 2; ++kk)                                   \
                    acc[(r0) + s][ni] = __builtin_amdgcn_mfma_f32_16x16x32_bf16( \
                        af[s][kk], bfr[ni][kk], acc[(r0) + s][ni], 0, 0, 0);     \
        __builtin_amdgcn_s_setprio(0);                                           \
    } while (0)

    f32x4 acc[8][4];
#pragma unroll
    for (int i = 0; i < 8; i++)
#pragma unroll
        for (int j = 0; j < 4; j++)
            acc[i][j] = (f32x4){0.f, 0.f, 0.f, 0.f};

    // ---- build-trickle state (MODE 0; requires NT == 16) ----
    const float* fsrc = nullptr;
    int   dbase = 0;
    f32x4 bl0 = {0.f, 0.f, 0.f, 0.f}, bl1 = {0.f, 0.f, 0.f, 0.f};
    float bgd = 0.f;
    if constexpr (MODE == 0) {
        const int qm = bx >> 2;
        fsrc  = (qm == 0) ? f0 : (qm == 1) ? f1 : (qm == 2) ? f2 : (qm == 3) ? f3 : f4;
        dbase = (bx & 3) * 256;
        const int br = t >> 5, bc = (t & 31) * 8;
        bl0 = *(const f32x4*)(fsrc + (rowBase + br) * 1024 + dbase + bc);
        bl1 = *(const f32x4*)(fsrc + (rowBase + br) * 1024 + dbase + bc + 4);
        bgd = g05[(rowBase + br) * 5 + (bx >> 2)];
    }

    // prologue: tile0 full -> buf0; tile1 {Bh0,Bh1,Ah0} -> buf1  (NT >= 2)
    STA(0, 0, 0, 128);
    STA(0, 0, 64, 192);
    STB(0, 0, 0);
    STB(0, 0, 128);
    STB(16384, 64, 0);
    STB(16384, 64, 128);
    STA(16384, 64, 0, 128);
    asm volatile("s_waitcnt vmcnt(6)" ::: "memory");   // tile0 landed
    BAR();

    bf16x8 afA[2][2], afB[2][2], bfr[4][2];
    RDAF(afA, 0, 0);      // tile0 q0 A-frags (cold, once)
    RDB(0);               // tile0 B-frags (cold, once)

    for (int tt = 0; tt < NT; ++tt) {
        const int c  = (tt & 1) << 14;
        const int cn = c ^ 16384;
        const int e1 = ((tt + 1 < NT) ? tt + 1 : NT - 1) << 6;
        const int e2 = ((tt + 2 < NT) ? tt + 2 : NT - 1) << 6;

        // ---- q0: MFMA(afA->0,1) | read afB(q1) | stage A(t+1)h1 | trickle ----
        if constexpr (MODE == 0) {
            const int idx = tt * 512 + t;
            const int br  = idx >> 5;
            const int bc  = (idx & 31) * 8;
            ushort8 bv;
            bv[0] = f2bf(bgd * bl0[0]); bv[1] = f2bf(bgd * bl0[1]);
            bv[2] = f2bf(bgd * bl0[2]); bv[3] = f2bf(bgd * bl0[3]);
            bv[4] = f2bf(bgd * bl1[0]); bv[5] = f2bf(bgd * bl1[1]);
            bv[6] = f2bf(bgd * bl1[2]); bv[7] = f2bf(bgd * bl1[3]);
            *(ushort8*)((u16*)Cout + (rowBase + br) * (size_t)ldc
                        + 5184 + colBase + bc) = bv;
            const int t2   = (tt + 1 < 16) ? tt + 1 : 15;   // select, no branch
            const int idx2 = t2 * 512 + t;
            const int br2  = idx2 >> 5;
            const int bc2  = (idx2 & 31) * 8;
            bl0 = *(const f32x4*)(fsrc + (rowBase + br2) * 1024 + dbase + bc2);
            bl1 = *(const f32x4*)(fsrc + (rowBase + br2) * 1024 + dbase + bc2 + 4);
            bgd = g05[(rowBase + br2) * 5 + (bx >> 2)];
        }
        STA(cn, e1, 64, 192);
        RDAF(afB, c, 1);
        MMX(afA, 0);
        sgb_q<(MODE == 0) ? 6 : 2>();
        BAR();

        // ---- q1: MFMA(afB->2,3) | read afA(q2) | stage B(t+2)h0 ----
        STB(c, e2, 0);
        RDAF(afA, c, 2);
        MMX(afB, 2);
        sgb_q<2>();
        BAR();

        // ---- q2: MFMA(afA->4,5) | read afB(q3) | stage B(t+2)h1 | vmcnt(4) ----
        STB(c, e2, 128);
        RDAF(afB, c, 3);
        MMX(afA, 4);
        sgb_q<2>();
        asm volatile("s_waitcnt vmcnt(4)" ::: "memory");   // tile t+1 fully landed
        BAR();

        // ---- q3: MFMA(afB->6,7) | prefetch afA(t+1,q0) + bfr(t+1) | stage A(t+2)h0 ----
        STA(c, e2, 0, 128);
        RDAF(afA, cn, 0);
        MMX(afB, 6);
        RDB(cn);             // WAR on bfr pins these after q3's MFMAs
        sgb_q3();
        BAR();
    }

    const int orow = wm * 128 + lhi * 4;
    const int ocol = colBase + wn * 64 + l16;

    if constexpr (MODE == 0) {
        u16* C = (u16*)Cout;
        const int eidx = colBase >> 10;
#pragma unroll
        for (int mi = 0; mi < 8; mi++) {
#pragma unroll
            for (int j = 0; j < 4; j++) {
                size_t r = rowBase + orow + mi * 16 + j;
                float w = fw05[r * 5 + eidx];
#pragma unroll
                for (int ni = 0; ni < 4; ni++) {
                    int cc = ocol + ni * 16;
                    float v = acc[mi][ni][j] + bias[cc];
                    float s = v / (1.f + __expf(-v));   // silu
                    C[r * (size_t)ldc + cc] = f2bf(w * s);
                }
            }
        }
    } else {
        float* C = (float*)Cout;
#pragma unroll
        for (int mi = 0; mi < 8; mi++) {
#pragma unroll
            for (int j = 0; j < 4; j++) {
                size_t r = rowBase + orow + mi * 16 + j;
#pragma unroll
                for (int ni = 0; ni < 4; ni++) {
                    size_t idx = r * (size_t)ldc + (ocol + ni * 16);
                    C[idx] = acc[mi][ni][j];
                }
            }
        }
    }
#undef STA
#undef STB
#undef RDAF
#undef RDB
#undef MMX
}

// ---------------------------------------------------------------------------
// Router + fused finalize. Per block: 64 rows.
//   logits[r][0..79] = x[r] . {Wsoft(5) | Wsparse(5) | m_key(64) | Wg(5)},
//   staged in LDS (Ws region, dead after k-loop); lanes 0..63 then run the
//   per-row finalize writing fw05, g05 and Abuf tail columns directly.
//   Also emits Xbf = bf16(x). No global logits round-trip.
//   [r14 bug fixed: m_val preload must be STRIDED — block has 256 threads,
//    `if (t<320)` left mvp[256..319] stale -> absmax 0.023.]
// ---------------------------------------------------------------------------
__global__ __launch_bounds__(256)
void router_kernel(const float* __restrict__ x,
                   const float* __restrict__ Wsoft, const float* __restrict__ Wsparse,
                   const float* __restrict__ m_key, const float* __restrict__ Wg,
                   const float* __restrict__ bsoft, const float* __restrict__ bsparse,
                   const float* __restrict__ bg, const float* __restrict__ m_val,
                   float* __restrict__ fw05, float* __restrict__ g05,
                   u16* __restrict__ Abuf, u16* __restrict__ Xbf)
{
    __shared__ float Xs[128][66];
    __shared__ float Ws[80][132];

    const int t    = threadIdx.x;
    const int lane = t & 63;
    const int wave = t >> 6;
    const int row0 = blockIdx.x * 64;

    float acc[20];
#pragma unroll
    for (int c = 0; c < 20; c++) acc[c] = 0.f;

    for (int k0 = 0; k0 < 1024; k0 += 128) {
#pragma unroll
        for (int i = 0; i < 8; i++) {
            int f4 = i * 256 + t;
            int r  = f4 >> 5;
            int kk = (f4 & 31) * 4;
            f32x4 v = *(const f32x4*)(x + (size_t)(row0 + r) * 1024 + k0 + kk);
            Xs[kk + 0][r] = v[0]; Xs[kk + 1][r] = v[1];
            Xs[kk + 2][r] = v[2]; Xs[kk + 3][r] = v[3];
            ushort4v o4;
            o4[0] = f2bf(v[0]); o4[1] = f2bf(v[1]);
            o4[2] = f2bf(v[2]); o4[3] = f2bf(v[3]);
            *(ushort4v*)(Xbf + (size_t)(row0 + r) * 1024 + k0 + kk) = o4;
        }
#pragma unroll
        for (int i = 0; i < 10; i++) {
            int f4 = i * 256 + t;
            int j  = f4 >> 5;
            int kk = (f4 & 31) * 4;
            const float* src;
            if      (j < 5)  src = Wsoft   + (size_t)j * 1024;
            else if (j < 10) src = Wsparse + (size_t)(j - 5) * 1024;
            else if (j < 74) src = m_key   + (size_t)(j - 10) * 1024;
            else             src = Wg      + (size_t)(j - 74) * 1024;
            *(f32x4*)&Ws[j][kk] = *(const f32x4*)(src + k0 + kk);
        }
        __syncthreads();

        for (int k4 = 0; k4 < 32; k4++) {
            float x0 = Xs[k4 * 4 + 0][lane];
            float x1 = Xs[k4 * 4 + 1][lane];
            float x2 = Xs[k4 * 4 + 2][lane];
            float x3 = Xs[k4 * 4 + 3][lane];
#pragma unroll
            for (int c = 0; c < 20; c++) {
                f32x4 w = *(const f32x4*)&Ws[wave * 20 + c][k4 * 4];
                acc[c] += x0 * w[0] + x1 * w[1] + x2 * w[2] + x3 * w[3];
            }
        }
        __syncthreads();
    }

    // ---- fused finalize: stage logits in LDS (Xs/Ws dead after sync) ----
    float* Lsm = &Ws[0][0];              // [64][81]
    float* mvp = &Xs[0][0];              // [320]
#pragma unroll
    for (int c = 0; c < 20; c++)
        Lsm[lane * 81 + wave * 20 + c] = acc[c];
    for (int i = t; i < 320; i += 256) mvp[i] = m_val[i];   // STRIDED (r14 fix)
    __syncthreads();

    if (t < 64) {
        const int row = row0 + t;
        const float* L = &Lsm[t * 81];

        float sl[5];
#pragma unroll
        for (int e = 0; e < 5; e++) sl[e] = L[e] + bsoft[e];
        float sm = sl[0];
#pragma unroll
        for (int e = 1; e < 5; e++) sm = fmaxf(sm, sl[e]);
        float ssum = 0.f, swv[5];
#pragma unroll
        for (int e = 0; e < 5; e++) { swv[e] = __expf(sl[e] - sm); ssum += swv[e]; }
        float sinv = 1.f / ssum;

        int am = 0; float bv = L[5] + bsparse[0];
#pragma unroll
        for (int e = 1; e < 5; e++) {
            float v = L[5 + e] + bsparse[e];
            if (v > bv) { bv = v; am = e; }
        }

        float amax = -1e30f;
        for (int m = 0; m < 64; m++) amax = fmaxf(amax, L[10 + m] * 0.03125f);
        float asum = 0.f, mw[5] = {0.f, 0.f, 0.f, 0.f, 0.f};
        for (int m = 0; m < 64; m++) {
            float a = __expf(L[10 + m] * 0.03125f - amax);
            asum += a;
#pragma unroll
            for (int e = 0; e < 5; e++) mw[e] += a * mvp[m * 5 + e];
        }
        float ainv = 1.f / asum;
#pragma unroll
        for (int e = 0; e < 5; e++) mw[e] *= ainv;
        float mm = mw[0];
#pragma unroll
        for (int e = 1; e < 5; e++) mm = fmaxf(mm, mw[e]);
        float msum = 0.f, me[5];
#pragma unroll
        for (int e = 0; e < 5; e++) { me[e] = __expf(mw[e] - mm); msum += me[e]; }
        float minv = 1.f / msum;

        u16* ta = Abuf + (size_t)row * 10368;
#pragma unroll
        for (int e = 0; e < 5; e++) {
            float fv = 0.125f * ((e == am) ? 1.f : 0.f) + 0.125f * swv[e] * sinv
                     + 0.25f * me[e] * minv;
            fw05[(size_t)row * 5 + e] = fv;
            ta[5120 + e] = f2bf(fv);
        }
#pragma unroll
        for (int q = 0; q < 5; q++)
            g05[(size_t)row * 5 + q] = 0.5f / (1.f + __expf(-(L[74 + q] + bg[q])));

        for (int j = 5125; j < 5184; j++) ta[j] = 0;
        ta[10304] = f2bf(0.5f);
        for (int j = 10305; j < 10368; j++) ta[j] = 0;
    }
}

// ---------------------------------------------------------------------------
__global__ __launch_bounds__(256)
void cast_bf16_kernel(const float* __restrict__ src, u16* __restrict__ dst, size_t n)
{
    size_t i = ((size_t)blockIdx.x * 256 + threadIdx.x) * 8;
    if (i >= n) return;
    f32x4 a = *(const f32x4*)(src + i);
    f32x4 b = *(const f32x4*)(src + i + 4);
    ushort8 o;
    o[0] = f2bf(a[0]); o[1] = f2bf(a[1]); o[2] = f2bf(a[2]); o[3] = f2bf(a[3]);
    o[4] = f2bf(b[0]); o[5] = f2bf(b[1]); o[6] = f2bf(b[2]); o[7] = f2bf(b[3]);
    *(ushort8*)(dst + i) = o;
}

// Wcat[o][c], ld 10368: c<5120: W2[e][o][d]; c=5120+e: b2[e][o]; c<5184: 0;
// c2=c-5184<5120: Wf[o][c2]; c2==5120: bf[o]; else 0.
__global__ __launch_bounds__(256)
void prep_wcat(const float* __restrict__ W2, const float* __restrict__ b2,
               const float* __restrict__ Wf, const float* __restrict__ bfias,
               u16* __restrict__ out)
{
    size_t tid = (size_t)blockIdx.x * 256 + threadIdx.x;   // 1024*1296
    int o  = (int)(tid / 1296);
    int c0 = (int)(tid % 1296) * 8;
    ushort8 v;
    if (c0 + 8 <= 5120) {
        int e = c0 >> 10, d = c0 & 1023;
        const float* s = W2 + ((size_t)e * 1024 + o) * 1024 + d;
        f32x4 a = *(const f32x4*)s;
        f32x4 b = *(const f32x4*)(s + 4);
        v[0] = f2bf(a[0]); v[1] = f2bf(a[1]); v[2] = f2bf(a[2]); v[3] = f2bf(a[3]);
        v[4] = f2bf(b[0]); v[5] = f2bf(b[1]); v[6] = f2bf(b[2]); v[7] = f2bf(b[3]);
    } else if (c0 < 5184) {
#pragma unroll
        for (int jj = 0; jj < 8; jj++) {
            int c = c0 + jj;
            float f = (c >= 5120 && c < 5125) ? b2[(size_t)(c - 5120) * 1024 + o] : 0.f;
            v[jj] = f2bf(f);
        }
    } else {
        int c2 = c0 - 5184;
        if (c2 + 8 <= 5120) {
            const float* s = Wf + (size_t)o * 5120 + c2;
            f32x4 a = *(const f32x4*)s;
            f32x4 b = *(const f32x4*)(s + 4);
            v[0] = f2bf(a[0]); v[1] = f2bf(a[1]); v[2] = f2bf(a[2]); v[3] = f2bf(a[3]);
            v[4] = f2bf(b[0]); v[5] = f2bf(b[1]); v[6] = f2bf(b[2]); v[7] = f2bf(b[3]);
        } else {
#pragma unroll
            for (int jj = 0; jj < 8; jj++) {
                int cj = c2 + jj;
                v[jj] = f2bf((cj == 5120) ? bfias[o] : 0.f);
            }
        }
    }
    *(ushort8*)(out + (size_t)o * 10368 + c0) = v;
}

// ---------------------------------------------------------------------------
extern "C" void kernel_launch(void* const* d_in, const int* in_sizes, int n_in,
                              void* d_out, int out_size, void* d_ws, size_t ws_size,
                              hipStream_t stream)
{
    (void)in_sizes; (void)n_in; (void)out_size;

    const float* x      = (const float*)d_in[0];
    const float* spect  = (const float*)d_in[1];
    const float* wavef  = (const float*)d_in[2];
    const float* pitch  = (const float*)d_in[3];
    const float* envel  = (const float*)d_in[4];
    const float* phase  = (const float*)d_in[5];
    const float* Wsoft  = (const float*)d_in[6];
    const float* bsoft  = (const float*)d_in[7];
    const float* Wsparse= (const float*)d_in[8];
    const float* bsparse= (const float*)d_in[9];
    const float* m_key  = (const float*)d_in[10];
    const float* m_val  = (const float*)d_in[11];
    const float* W1     = (const float*)d_in[12];
    const float* b1     = (const float*)d_in[13];
    const float* W2     = (const float*)d_in[14];
    const float* b2     = (const float*)d_in[15];
    const float* Wg     = (const float*)d_in[16];
    const float* bg     = (const float*)d_in[17];
    const float* Wf     = (const float*)d_in[18];
    const float* bfias  = (const float*)d_in[19];
    float* out = (float*)d_out;

    const int N = 16384;

    // per-row: Xbf 2048 + Abuf 20736 + fw05 20 + g05 20 = 22824 B
    size_t fixed = (size_t)5 * 1024 * 1024 * 2 + (size_t)1024 * 10368 * 2;
    int NC = 16384;
    while (NC > 256 && fixed + (size_t)NC * 22824 > ws_size) NC >>= 1;

    char* p = (char*)d_ws;
    u16* W1bf = (u16*)p; p += (size_t)5 * 1024 * 1024 * 2;
    u16* Wcat = (u16*)p; p += (size_t)1024 * 10368 * 2;
    u16* Xbf  = (u16*)p; p += (size_t)NC * 1024 * 2;
    u16* Abuf = (u16*)p; p += (size_t)NC * 10368 * 2;
    float* fw05 = (float*)p; p += (size_t)NC * 5 * 4;
    float* g05  = (float*)p; p += (size_t)NC * 5 * 4;

    // one-time weight prep (W1 flat IS the [5120][1024] concat: row e*1024+o)
    cast_bf16_kernel<<<2560, 256, 0, stream>>>(W1, W1bf, (size_t)5 * 1024 * 1024);
    prep_wcat<<<5184, 256, 0, stream>>>(W2, b2, Wf, bfias, Wcat);

    for (int n0 = 0; n0 < N; n0 += NC) {
        const size_t off = (size_t)n0 * 1024;

        // router + fused finalize (writes fw05, g05, Abuf tails, Xbf)
        router_kernel<<<NC / 64, 256, 0, stream>>>(
            x + off, Wsoft, Wsparse, m_key, Wg,
            bsoft, bsparse, bg, m_val, fw05, g05, Abuf, Xbf);

        // Abuf[:,0:5120] = fw05_e * silu(X @ W1^T + b1); simultaneously
        // trickle-builds Abuf[:,5184:10304] = g * feat (1 chunk/thread/K-tile)
        gemm256<0><<<dim3(20, NC / 256), 512, 0, stream>>>(
            Xbf, 1024, W1bf, 1024, 1024, Abuf, 10368, b1, fw05, g05,
            spect + off, wavef + off, pitch + off, envel + off, phase + off);

        // out = 0.5*moe + 0.5*fused in one K=10368 GEMM
        gemm256<1><<<dim3(4, NC / 256), 512, 0, stream>>>(
            Abuf, 10368, Wcat, 10368, 10368, out + off, 1024,
            nullptr, nullptr, nullptr, nullptr, nullptr, nullptr, nullptr, nullptr);
    }
}